// Round 8
// baseline (671.055 us; speedup 1.0000x reference)
//
#include <hip/hip_runtime.h>
#include <hip/hip_bf16.h>

// Problem constants (fixed by reference setup_inputs):
//   K3=27, PAIRS_PER_K=131072 (=2^17), N_VOX=262144 (=2^18), C_IN=C_OUT=32
//   M = 3,538,944 pairs. out = [262144][32] fp32.
//
// History: R1 113M fp32 atomics = 5.9ms. R2 per-thread LDS W = 3x FMA floor.
// R3 scalar gather latency-bound. R4 MFMA gather 312us. R5 dist-4 prefetch
// regressed (VALU 2.4x, occupancy halved). R6 runtime-indexed private arrays
// -> scratch (RULE: named regs only). R7 split-k 298us: stalls = overflow
// dist-1 chains (~850cyc/entry) + HBM misses on 356MB fp32 random rows;
// VALU = strided W loads + cvt/mask.
// R8: bf16 feature table + zero-row (1 load, 0 VALU per row; halves bytes),
// transposed Wt (4x float4 vs 16 scalar), overflow batched 4-wide in NAMED
// regs, XCD-affine build passes.

#define N_VOX    262144
#define LOG2_NV  18
#define C_CH     32
#define K3       27
#define LOG2_PPK 17
#define BLOCK    256
#define FLAG_FIN 0x40000000
#define ECAP     4096
#define PLPAD    36

typedef __attribute__((ext_vector_type(8))) short bf16x8;
typedef __attribute__((ext_vector_type(4))) float f32x4;

__device__ __forceinline__ unsigned short f2bf(float f) {
  union { __hip_bfloat16 h; unsigned short u; } cv;
  cv.h = __float2bfloat16(f);
  return cv.u;
}
__device__ __forceinline__ float bflo(unsigned u) {
  union { unsigned v; float f; } c; c.v = u << 16; return c.f;
}
__device__ __forceinline__ float bfhi(unsigned u) {
  union { unsigned v; float f; } c; c.v = u & 0xFFFF0000u; return c.f;
}

// dot of 16 bf16 (two uint4) against 16 contiguous fp32 weights.
__device__ __forceinline__ float dot16bf(uint4 a, uint4 b, const float4* wv) {
  float4 w0 = wv[0], w1 = wv[1], w2 = wv[2], w3 = wv[3];
  float s = 0.f;
  s = fmaf(bflo(a.x), w0.x, s); s = fmaf(bfhi(a.x), w0.y, s);
  s = fmaf(bflo(a.y), w0.z, s); s = fmaf(bfhi(a.y), w0.w, s);
  s = fmaf(bflo(a.z), w1.x, s); s = fmaf(bfhi(a.z), w1.y, s);
  s = fmaf(bflo(a.w), w1.z, s); s = fmaf(bfhi(a.w), w1.w, s);
  s = fmaf(bflo(b.x), w2.x, s); s = fmaf(bfhi(b.x), w2.y, s);
  s = fmaf(bflo(b.y), w2.z, s); s = fmaf(bfhi(b.y), w2.w, s);
  s = fmaf(bflo(b.z), w3.x, s); s = fmaf(bfhi(b.z), w3.y, s);
  s = fmaf(bflo(b.w), w3.z, s); s = fmaf(bfhi(b.w), w3.w, s);
  return s;
}
__device__ __forceinline__ float dot16f(float4 a0, float4 a1, float4 a2,
                                        float4 a3, const float4* wv) {
  float4 w0 = wv[0], w1 = wv[1], w2 = wv[2], w3 = wv[3];
  float s = 0.f;
  s = fmaf(a0.x, w0.x, s); s = fmaf(a0.y, w0.y, s);
  s = fmaf(a0.z, w0.z, s); s = fmaf(a0.w, w0.w, s);
  s = fmaf(a1.x, w1.x, s); s = fmaf(a1.y, w1.y, s);
  s = fmaf(a1.z, w1.z, s); s = fmaf(a1.w, w1.w, s);
  s = fmaf(a2.x, w2.x, s); s = fmaf(a2.y, w2.y, s);
  s = fmaf(a2.z, w2.z, s); s = fmaf(a2.w, w2.w, s);
  s = fmaf(a3.x, w3.x, s); s = fmaf(a3.y, w3.y, s);
  s = fmaf(a3.z, w3.z, s); s = fmaf(a3.w, w3.w, s);
  return s;
}

// ---------------------------------------------------------------------------
// bf16 feature table: row v<N_VOX = bf16(in_feature[v]); row N_VOX = zeros.
__global__ __launch_bounds__(BLOCK) void ifb_prep_kernel(
    const float* __restrict__ in_feature, unsigned short* __restrict__ ifb) {
  int idx = blockIdx.x * BLOCK + threadIdx.x;       // 8 shorts per thread
  const int lim = N_VOX * C_CH / 8;                 // 1,048,576
  if (idx >= lim + 4) return;
  union { unsigned short u[8]; uint4 v; } pk;
  if (idx < lim) {
    const float4* src = (const float4*)(in_feature + (idx << 3));
    float4 f0 = src[0], f1 = src[1];
    pk.u[0] = f2bf(f0.x); pk.u[1] = f2bf(f0.y);
    pk.u[2] = f2bf(f0.z); pk.u[3] = f2bf(f0.w);
    pk.u[4] = f2bf(f1.x); pk.u[5] = f2bf(f1.y);
    pk.u[6] = f2bf(f1.z); pk.u[7] = f2bf(f1.w);
  } else {
    pk.v = make_uint4(0, 0, 0, 0);                  // zero row (index N_VOX)
  }
  ((uint4*)ifb)[idx] = pk.v;
}

// Transposed weights Wt[k][c][i] = W[k][i][c] (c-major -> contiguous i).
__global__ __launch_bounds__(BLOCK) void wt_prep_kernel(
    const float* __restrict__ kernel_w, float* __restrict__ wt) {
  int tid = blockIdx.x * BLOCK + threadIdx.x;
  if (tid >= K3 * 1024) return;
  int k = tid >> 10, rem = tid & 1023, c = rem >> 5, i = rem & 31;
  wt[(k << 10) + (c << 5) + i] = kernel_w[(k << 10) + (i << 5) + c];
}

// B-fragment prep: W pre-permuted into mfma_16x16x32 B-operand lane layout
// (mirror of verified A layout A[m=lane&15][k=quad*8+j], m89/m91).
__global__ __launch_bounds__(BLOCK) void bf_prep_kernel(
    const float* __restrict__ kernel_w, unsigned short* __restrict__ Bf) {
  int tid = blockIdx.x * BLOCK + threadIdx.x;
  if (tid >= K3 * 2 * 64) return;
  int lane = tid & 63;
  int kc = tid >> 6;
  int k = kc >> 1, t = kc & 1;
  int i0 = (lane >> 4) * 8;
  int c = t * 16 + (lane & 15);
  union { unsigned short u[8]; uint4 v; } pk;
#pragma unroll
  for (int j = 0; j < 8; ++j)
    pk.u[j] = f2bf(kernel_w[(k << 10) + (i0 + j) * C_CH + c]);
  ((uint4*)Bf)[tid] = pk.v;
}

// ---------------------------------------------------------------------------
// Build passes, XCD-affine: plane k is only touched by blocks with
// blockIdx%8 == k%8 (heuristic round-robin block->XCD map; perf-only).
__global__ __launch_bounds__(BLOCK) void passA_kernel(
    const int2* __restrict__ nbmap, int* __restrict__ T) {
  int r = blockIdx.x & 7, m = blockIdx.x >> 3;
  int k = r + ((m >> 9) << 3);
  if (k >= K3) return;
  int p = (k << LOG2_PPK) + ((m & 511) << 8) + threadIdx.x;
  int2 nb = nbmap[p];
  T[(k << LOG2_NV) + nb.y] = p;
}

__global__ __launch_bounds__(BLOCK) void passB_kernel(
    const int2* __restrict__ nbmap, int* __restrict__ T,
    int* __restrict__ ovf_cnt, int* __restrict__ ovf, int S2,
    int* __restrict__ ecnt, int2* __restrict__ elist) {
  int r = blockIdx.x & 7, m = blockIdx.x >> 3;
  int k = r + ((m >> 9) << 3);
  if (k >= K3) return;
  int p = (k << LOG2_PPK) + ((m & 511) << 8) + threadIdx.x;
  int2 nb = nbmap[p];
  int idx = (k << LOG2_NV) + nb.y;
  if (T[idx] == p) {
    T[idx] = FLAG_FIN | nb.x;                 // in_idx < 2^18
  } else {
    int pos = atomicAdd(&ovf_cnt[nb.y], 1);
    if (pos < S2) {
      ovf[(pos << LOG2_NV) + nb.y] = (k << LOG2_NV) | nb.x;
    } else {
      int ep = atomicAdd(ecnt, 1);
      if (ep < ECAP) elist[ep] = make_int2(nb.y, (k << LOG2_NV) | nb.x);
    }
  }
}

// ---------------------------------------------------------------------------
// Split-k MFMA gather. Block = 4 waves x same 16 voxels; wave w owns 7 k's.
// USE_IFB=1: rows from bf16 table (1 load, no cvt/mask via zero-row).
template <int USE_IFB>
__global__ __launch_bounds__(BLOCK) void gather_splitk2_kernel(
    const float* __restrict__ in_feature,
    const unsigned short* __restrict__ ifb,
    const float* __restrict__ wt,          // [27][32][32] c-major
    const float* __restrict__ bias,
    const int* __restrict__ T,
    const int* __restrict__ ovf_cnt,
    const int* __restrict__ ovf,
    const unsigned short* __restrict__ Bf,
    float* __restrict__ out, int S2) {
  __shared__ float plane[4][16][PLPAD];
  __shared__ int flatE[256];
  __shared__ int scnt[16];

  const int tid = threadIdx.x;
  const int w = tid >> 6;
  const int lane = tid & 63;
  const int r16 = lane & 15;
  const int quad = lane >> 4;
  const int vb = blockIdx.x << 4;

  // ---- overflow staging ----
  if (tid < 16) {
    int c = ovf_cnt[vb + tid];
    scnt[tid] = c < S2 ? c : S2;
  }
  __syncthreads();
  const int er = tid & 15, ej = tid >> 4;
  int myb = 0, tot = 0;
#pragma unroll
  for (int q = 0; q < 16; ++q) {
    int cq = scnt[q];
    if (q < er) myb += cq;
    tot += cq;
  }
  if (ej < scnt[er])
    flatE[myb + ej] = (er << 24) | ovf[(ej << LOG2_NV) + vb + er];
  __syncthreads();

  // ---- phase A: this wave's 7 probes, one round trip ----
  const int kb = w * 7;
  const int kn = (w == 3) ? 6 : 7;
  const int v = vb + r16;
  int tv[7];
#pragma unroll
  for (int d = 0; d < 7; ++d)
    tv[d] = (d < kn) ? T[((kb + d) << LOG2_NV) + v] : -1;

  // ---- phase B: this wave's rows, one round trip ----
  bf16x8 R[7];
  if (USE_IFB) {
#pragma unroll
    for (int d = 0; d < 7; ++d) {
      int t = tv[d];
      int in = (t >= 0) ? (t & 0x3FFFF) : N_VOX;   // invalid -> zero row
      union { uint4 u; bf16x8 h; } cv;
      cv.u = *(const uint4*)(ifb + (in << 5) + (quad << 3));
      R[d] = cv.h;
    }
  } else {
#pragma unroll
    for (int d = 0; d < 7; ++d) {
      int t = tv[d];
      int in = (t >= 0) ? (t & 0x3FFFF) : 0;
      const float4* ap = (const float4*)(in_feature + (in << 5) + (quad << 3));
      float4 f0 = ap[0], f1 = ap[1];
      bf16x8 a;
      a[0] = (short)f2bf(f0.x); a[1] = (short)f2bf(f0.y);
      a[2] = (short)f2bf(f0.z); a[3] = (short)f2bf(f0.w);
      a[4] = (short)f2bf(f1.x); a[5] = (short)f2bf(f1.y);
      a[6] = (short)f2bf(f1.z); a[7] = (short)f2bf(f1.w);
      if (t < 0) a = (bf16x8)0;
      R[d] = a;
    }
  }

  // ---- phase C: 14 MFMAs ----
  f32x4 acc0 = {0.f, 0.f, 0.f, 0.f};
  f32x4 acc1 = {0.f, 0.f, 0.f, 0.f};
  const uint4* bfp = (const uint4*)Bf;
#pragma unroll
  for (int d = 0; d < 7; ++d) {
    if (d < kn) {
      int k = kb + d;
      uint4 raw0 = bfp[(k * 2 + 0) * 64 + lane];
      uint4 raw1 = bfp[(k * 2 + 1) * 64 + lane];
      bf16x8 b0 = *reinterpret_cast<const bf16x8*>(&raw0);
      bf16x8 b1 = *reinterpret_cast<const bf16x8*>(&raw1);
      acc0 = __builtin_amdgcn_mfma_f32_16x16x32_bf16(R[d], b0, acc0, 0, 0, 0);
      acc1 = __builtin_amdgcn_mfma_f32_16x16x32_bf16(R[d], b1, acc1, 0, 0, 0);
    }
  }

  // ---- dump partials (C/D: col=lane&15, row=quad*4+reg — m89/m91) ----
#pragma unroll
  for (int reg = 0; reg < 4; ++reg) {
    int row = quad * 4 + reg;
    plane[w][row][r16] = acc0[reg];
    plane[w][row][16 + r16] = acc1[reg];
  }

  // ---- overflow: wave w takes flat entries w+4t, batched 4/group ----
  const int c32 = lane & 31, h = lane >> 5;
  if (tot > w) {
    const int cnt_w = (tot - 1 - w) / 4 + 1;
    const int ngroups = (cnt_w + 3) >> 2;
    for (int g = 0; g < ngroups; ++g) {
      const int i0 = w + (g << 4);               // entries i0, i0+4, +8, +12
      const int f0 = i0, f1 = i0 + 4, f2 = i0 + 8, f3 = i0 + 12;
      const int e0 = flatE[f0 < tot ? f0 : 0];
      const int e1 = flatE[f1 < tot ? f1 : 0];
      const int e2 = flatE[f2 < tot ? f2 : 0];
      const int e3 = flatE[f3 < tot ? f3 : 0];
      if (USE_IFB) {
        // 4 independent bf16 row loads (32B/lane each): one round trip
        const uint4* r0 = (const uint4*)(ifb + ((e0 & 0x3FFFF) << 5) + (h << 4));
        const uint4* r1 = (const uint4*)(ifb + ((e1 & 0x3FFFF) << 5) + (h << 4));
        const uint4* r2 = (const uint4*)(ifb + ((e2 & 0x3FFFF) << 5) + (h << 4));
        const uint4* r3 = (const uint4*)(ifb + ((e3 & 0x3FFFF) << 5) + (h << 4));
        uint4 a0l = r0[0], a0h = r0[1];
        uint4 a1l = r1[0], a1h = r1[1];
        uint4 a2l = r2[0], a2h = r2[1];
        uint4 a3l = r3[0], a3h = r3[1];
#pragma unroll
        for (int j = 0; j < 4; ++j) {
          const int fj = i0 + (j << 2);
          const int e = (j == 0) ? e0 : (j == 1) ? e1 : (j == 2) ? e2 : e3;
          uint4 al = (j == 0) ? a0l : (j == 1) ? a1l : (j == 2) ? a2l : a3l;
          uint4 ah = (j == 0) ? a0h : (j == 1) ? a1h : (j == 2) ? a2h : a3h;
          const int k2 = (e >> LOG2_NV) & 31;
          const float4* wv =
              (const float4*)(wt + (k2 << 10) + (c32 << 5) + (h << 4));
          float psum = dot16bf(al, ah, wv);
          psum += __shfl_xor(psum, 32);
          if (h == 0 && fj < tot) plane[w][(e >> 24) & 15][c32] += psum;
        }
      } else {
        // fp32 rows, batch 2 per half-group (reg budget)
#pragma unroll
        for (int half = 0; half < 2; ++half) {
          const int fa = i0 + (half << 3), fb = fa + 4;
          const int ea = (half == 0) ? e0 : e2;
          const int eb = (half == 0) ? e1 : e3;
          const float4* ra =
              (const float4*)(in_feature + ((ea & 0x3FFFF) << 5) + (h << 4));
          const float4* rb =
              (const float4*)(in_feature + ((eb & 0x3FFFF) << 5) + (h << 4));
          float4 a0 = ra[0], a1 = ra[1], a2 = ra[2], a3 = ra[3];
          float4 b0 = rb[0], b1 = rb[1], b2 = rb[2], b3 = rb[3];
          const int ka = (ea >> LOG2_NV) & 31, kbk = (eb >> LOG2_NV) & 31;
          const float4* wva =
              (const float4*)(wt + (ka << 10) + (c32 << 5) + (h << 4));
          const float4* wvb =
              (const float4*)(wt + (kbk << 10) + (c32 << 5) + (h << 4));
          float pa = dot16f(a0, a1, a2, a3, wva);
          float pb = dot16f(b0, b1, b2, b3, wvb);
          pa += __shfl_xor(pa, 32);
          pb += __shfl_xor(pb, 32);
          if (h == 0 && fa < tot) plane[w][(ea >> 24) & 15][c32] += pa;
          if (h == 0 && fb < tot) plane[w][(eb >> 24) & 15][c32] += pb;
        }
      }
    }
  }

  // ---- merge 4 planes + bias ----
  __syncthreads();
  const int mr = tid >> 4;
  const int mc = (tid & 15) << 1;
  float s0 = plane[0][mr][mc] + plane[1][mr][mc] + plane[2][mr][mc] +
             plane[3][mr][mc] + bias[mc];
  float s1 = plane[0][mr][mc + 1] + plane[1][mr][mc + 1] +
             plane[2][mr][mc + 1] + plane[3][mr][mc + 1] + bias[mc + 1];
  float2 o; o.x = s0; o.y = s1;
  *(float2*)(out + ((vb + mr) << 5) + mc) = o;
}

// ---------------------------------------------------------------------------
// Emergency finisher (entries beyond S2; expected ~0).
__global__ __launch_bounds__(BLOCK) void emergency_kernel(
    const float* __restrict__ in_feature, const float* __restrict__ kernel_w,
    const int* __restrict__ ecnt, const int2* __restrict__ elist,
    float* __restrict__ out) {
  int e = blockIdx.x * BLOCK + threadIdx.x;
  int n = *ecnt;
  if (n > ECAP) n = ECAP;
  if (e >= n) return;
  int2 ent = elist[e];
  int v = ent.x, k = ent.y >> LOG2_NV, in = ent.y & 0x3FFFF;
  float a[C_CH];
  const float4* ar = (const float4*)(in_feature + (in << 5));
#pragma unroll
  for (int q = 0; q < 8; ++q) ((float4*)a)[q] = ar[q];
  for (int c = 0; c < C_CH; ++c) {
    float s = 0.f;
#pragma unroll
    for (int i = 0; i < C_CH; ++i)
      s = fmaf(a[i], kernel_w[(k << 10) + i * C_CH + c], s);
    atomicAdd(&out[v * C_CH + c], s);
  }
}

// ---------------------------------------------------------------------------
// Fallback (tiny ws): round-1 direct-atomic version. Correct, slow.
__global__ __launch_bounds__(BLOCK) void init_bias_kernel(
    float* __restrict__ out, const float* __restrict__ bias, int n4) {
  int idx = blockIdx.x * blockDim.x + threadIdx.x;
  if (idx >= n4) return;
  ((float4*)out)[idx] = ((const float4*)bias)[idx & 7];
}

__global__ __launch_bounds__(BLOCK) void scatter_conv_kernel(
    const float* __restrict__ in_feature, const float* __restrict__ kernel_w,
    const int* __restrict__ nbmap, float* __restrict__ out) {
  const int k = blockIdx.x >> 9;
  const int pair = blockIdx.x * BLOCK + threadIdx.x;
  const float* __restrict__ Wk = kernel_w + k * (C_CH * C_CH);
  const int2 nb = ((const int2*)nbmap)[pair];
  const float4* __restrict__ inrow =
      (const float4*)(in_feature + (long)nb.x * C_CH);
  float a[C_CH];
#pragma unroll
  for (int j = 0; j < 8; ++j) ((float4*)a)[j] = inrow[j];
  float acc[C_CH];
#pragma unroll
  for (int c = 0; c < C_CH; ++c) acc[c] = 0.0f;
#pragma unroll
  for (int i = 0; i < C_CH; ++i) {
    const float av = a[i];
#pragma unroll
    for (int c = 0; c < C_CH; ++c)
      acc[c] = fmaf(av, Wk[i * C_CH + c], acc[c]);
  }
  float* __restrict__ orow = out + (long)nb.y * C_CH;
#pragma unroll
  for (int c = 0; c < C_CH; ++c) atomicAdd(orow + c, acc[c]);
}

// ===========================================================================
extern "C" void kernel_launch(void* const* d_in, const int* in_sizes, int n_in,
                              void* d_out, int out_size, void* d_ws,
                              size_t ws_size, hipStream_t stream) {
  const float* in_feature = (const float*)d_in[0];
  const float* kernel_w   = (const float*)d_in[1];
  const float* bias       = (const float*)d_in[2];
  const int*   nbmap      = (const int*)d_in[3];
  float* out = (float*)d_out;
  const int M = in_sizes[3] / 2;                 // 3,538,944

  // ws (ints): T[27N] | cnt[N] | ecnt[64] | elist[2*ECAP] | Bf[13824]
  //            | Wt[27648] | [ifb 4,194,320] | ovf[S2*N]
  const long FIXED = 64 + 2 * ECAP + 13824 + 27648;
  const long IFB_I = 4194320;                    // 262145*32 shorts
  long ws_ints = (long)(ws_size / 4);
  long cap_ifb = (ws_ints - FIXED - IFB_I) / N_VOX - (K3 + 1);
  long cap_fp  = (ws_ints - FIXED) / N_VOX - (K3 + 1);
  const int use_ifb = (cap_ifb >= 10);
  long s2_cap = use_ifb ? cap_ifb : cap_fp;
  int S2 = (int)(s2_cap > 15 ? 15 : s2_cap);

  if (S2 < 4) {                                  // tiny ws: direct atomics
    const int n4 = out_size / 4;
    init_bias_kernel<<<(n4 + BLOCK - 1) / BLOCK, BLOCK, 0, stream>>>(out, bias,
                                                                     n4);
    scatter_conv_kernel<<<M / BLOCK, BLOCK, 0, stream>>>(in_feature, kernel_w,
                                                         nbmap, out);
    return;
  }

  int* T        = (int*)d_ws;                       // [27][N_VOX]
  int* ovf_cnt  = T + (long)K3 * N_VOX;             // [N_VOX]
  int* ecnt     = ovf_cnt + N_VOX;                  // [64] (use [0])
  int2* elist   = (int2*)(ecnt + 64);               // [ECAP]
  unsigned short* Bf = (unsigned short*)(ecnt + 64 + 2 * ECAP);  // [27648]
  float* wt     = (float*)(Bf + 2 * 13824);         // [27648]
  int* after_wt = (int*)(wt + 27648);
  unsigned short* ifb = (unsigned short*)after_wt;  // [262145][32] (opt)
  int* ovf = use_ifb ? (after_wt + IFB_I) : after_wt;  // [S2][N_VOX]

  hipMemsetAsync(T, 0xFF, (size_t)K3 * N_VOX * 4, stream);
  hipMemsetAsync(ovf_cnt, 0, (size_t)(N_VOX + 64) * 4, stream);

  bf_prep_kernel<<<(K3 * 2 * 64 + BLOCK - 1) / BLOCK, BLOCK, 0, stream>>>(
      kernel_w, Bf);
  wt_prep_kernel<<<(K3 * 1024 + BLOCK - 1) / BLOCK, BLOCK, 0, stream>>>(
      kernel_w, wt);
  if (use_ifb)
    ifb_prep_kernel<<<(N_VOX * C_CH / 8 + 4 + BLOCK - 1) / BLOCK, BLOCK, 0,
                      stream>>>(in_feature, ifb);

  passA_kernel<<<16384, BLOCK, 0, stream>>>((const int2*)nbmap, T);
  passB_kernel<<<16384, BLOCK, 0, stream>>>((const int2*)nbmap, T, ovf_cnt,
                                            ovf, S2, ecnt, elist);
  if (use_ifb)
    gather_splitk2_kernel<1><<<N_VOX / 16, BLOCK, 0, stream>>>(
        in_feature, ifb, wt, bias, T, ovf_cnt, ovf, Bf, out, S2);
  else
    gather_splitk2_kernel<0><<<N_VOX / 16, BLOCK, 0, stream>>>(
        in_feature, ifb, wt, bias, T, ovf_cnt, ovf, Bf, out, S2);
  emergency_kernel<<<ECAP / BLOCK, BLOCK, 0, stream>>>(in_feature, kernel_w,
                                                       ecnt, elist, out);
}